// Round 6
// baseline (1617.414 us; speedup 1.0000x reference)
//
#include <hip/hip_runtime.h>
#include <hip/hip_bf16.h>

// ---- types ----
typedef _Float16 f16x8 __attribute__((ext_vector_type(8)));
typedef _Float16 f16x4 __attribute__((ext_vector_type(4)));
typedef float f32x4 __attribute__((ext_vector_type(4)));

// Problem constants: S=2048, B=32, D_IN=512, H=1024, PROJ=512, L=2
#define SEQ 2048
#define BATCH 32
#define DIN 512
#define HID 1024
#define PROJ 512
#define ROWS (SEQ*BATCH)          // 65536
#define G3H (3*HID)               // 3072
#define NSEG 16
#define NCHAIN (BATCH*HID)        // 32768 scan chains

#define AS1(p) ((const __attribute__((address_space(1))) void*)(p))
#define AS3(p) ((__attribute__((address_space(3))) void*)(p))

// ---------------- fp32 -> fp16 conversion ----------------
__global__ __launch_bounds__(256)
void cvt_f32_f16(const float* __restrict__ in, _Float16* __restrict__ out, int n4)
{
    int i = blockIdx.x * 256 + threadIdx.x;
    if (i >= n4) return;
    float4 v = ((const float4*)in)[i];
    f16x4 o;
    o[0] = (_Float16)v.x; o[1] = (_Float16)v.y;
    o[2] = (_Float16)v.z; o[3] = (_Float16)v.w;
    ((f16x4*)out)[i] = o;
}

// ---------------- GEMM: C(M,N) = A(M,K) * B(N,K)^T, fp16 in, fp32 acc ------
// 256x128 tile, BK=64, 8 waves (4M x 2N), per-wave 64x64 output.
// 3-deep rotating LDS buffers, counted vmcnt(6) (never 0 in steady state),
// per-phase interleave {ds_read || global_load_lds -> bar -> lgkm0 ->
// setprio1 -> 16 MFMA -> setprio0 -> bar}, 2 phases (ks=0/1) per K-tile.
// LDS rows are 128B with byte ^= ((row&7)<<4) XOR swizzle applied BOTH on the
// pre-swizzled global staging source and on the ds_read offsets (rule 21).
// LDS: A 3x32KB + B 3x16KB = 144 KiB dynamic.
// MODE 0: epilogue +bias, col<HH -> tanh else sigmoid, store fp16 (gates)
// MODE 1: plain store fp16
template<int MODE>
__global__ __launch_bounds__(512)
void gemm_lds(const _Float16* __restrict__ A, const _Float16* __restrict__ Bm,
              const float* __restrict__ bias, _Float16* __restrict__ C,
              int N, int K, int HH)
{
    extern __shared__ __align__(16) char smem[];
    char* sA = smem;               // 3 x 32768
    char* sB = smem + 98304;       // 3 x 16384

    const int tid  = threadIdx.x;
    const int lane = tid & 63;
    const int wave = tid >> 6;
    const int wm = wave & 3;           // M-wave 0..3 (rows wm*64..)
    const int wn = wave >> 2;          // N-wave 0..1 (cols wn*64..)
    const size_t row0 = (size_t)blockIdx.y * 256;
    const size_t col0 = (size_t)blockIdx.x * 128;
    const size_t Kb = (size_t)K * 2;

    const char* Ab = (const char*)A;
    const char* Bb = (const char*)Bm;

    const int rl = lane & 15;          // fragment row
    const int g  = lane >> 4;          // k-subgroup (8 fp16 = 16B each)
    const int swz = (rl & 7) << 4;     // read-side XOR (row&7 == rl&7)
    const int c0 = (g * 16) ^ swz;     // ks=0 column byte (swizzled)
    const int c1 = (64 + g * 16) ^ swz;// ks=1 column byte (swizzled)
    const int aBase = (wm * 64 + rl) * 128;
    const int bBase = (wn * 64 + rl) * 128;

    // staging geometry: per round 512 threads x 16B = 8KB = 64 rows of 128B.
    // source column is pre-swizzled so that the linear gload_lds dest +
    // swizzled read are a consistent involution (rule 21).
    const int srow = tid >> 3;                       // 0..63
    const int scb  = ((tid & 7) * 16) ^ ((srow & 7) << 4);

    f32x4 acc[4][4] = {};
    const int nk = K / 64;

#define STAGE_A(bufi, kt)                                                        \
    do { _Pragma("unroll")                                                       \
    for (int r = 0; r < 4; ++r) {                                                \
        const char* src = Ab + (row0 + r * 64 + srow) * Kb + (size_t)(kt) * 128 + scb; \
        __builtin_amdgcn_global_load_lds(AS1(src),                               \
            AS3(sA + (bufi) * 32768 + r * 8192 + wave * 1024), 16, 0, 0);        \
    } } while (0)
#define STAGE_B(bufi, kt)                                                        \
    do { _Pragma("unroll")                                                       \
    for (int r = 0; r < 2; ++r) {                                                \
        const char* src = Bb + (col0 + r * 64 + srow) * Kb + (size_t)(kt) * 128 + scb; \
        __builtin_amdgcn_global_load_lds(AS1(src),                               \
            AS3(sB + (bufi) * 16384 + r * 8192 + wave * 1024), 16, 0, 0);        \
    } } while (0)
#define BAR() asm volatile("s_barrier" ::: "memory")
#define LGKM0() do { asm volatile("s_waitcnt lgkmcnt(0)" ::: "memory");          \
                     __builtin_amdgcn_sched_barrier(0); } while (0)

    // prologue: stage tiles 0 and 1 (6 loads/wave each); wait tile0 only.
    STAGE_A(0, 0); STAGE_B(0, 0);
    STAGE_A(1, 1); STAGE_B(1, 1);
    asm volatile("s_waitcnt vmcnt(6)" ::: "memory");
    BAR();

    int buf = 0;
    for (int t = 0; t < nk; ++t) {
        const int nbuf = (buf >= 1) ? buf - 1 : buf + 2;   // (t+2)%3
        // ---------- phase ks=0 ----------
        f16x8 af[4], bf[4];
#pragma unroll
        for (int m = 0; m < 4; ++m)
            af[m] = *(const f16x8*)(sA + buf * 32768 + aBase + m * 2048 + c0);
#pragma unroll
        for (int n = 0; n < 4; ++n)
            bf[n] = *(const f16x8*)(sB + buf * 16384 + bBase + n * 2048 + c0);
        if (t + 2 < nk) STAGE_A(nbuf, t + 2);
        BAR();
        LGKM0();
        __builtin_amdgcn_s_setprio(1);
#pragma unroll
        for (int m = 0; m < 4; ++m)
#pragma unroll
            for (int n = 0; n < 4; ++n)
                acc[m][n] = __builtin_amdgcn_mfma_f32_16x16x32_f16(af[m], bf[n], acc[m][n], 0, 0, 0);
        __builtin_amdgcn_s_setprio(0);
        BAR();
        // ---------- phase ks=1 ----------
#pragma unroll
        for (int m = 0; m < 4; ++m)
            af[m] = *(const f16x8*)(sA + buf * 32768 + aBase + m * 2048 + c1);
#pragma unroll
        for (int n = 0; n < 4; ++n)
            bf[n] = *(const f16x8*)(sB + buf * 16384 + bBase + n * 2048 + c1);
        if (t + 2 < nk) STAGE_B(nbuf, t + 2);
        BAR();
        LGKM0();
        __builtin_amdgcn_s_setprio(1);
#pragma unroll
        for (int m = 0; m < 4; ++m)
#pragma unroll
            for (int n = 0; n < 4; ++n)
                acc[m][n] = __builtin_amdgcn_mfma_f32_16x16x32_f16(af[m], bf[n], acc[m][n], 0, 0, 0);
        __builtin_amdgcn_s_setprio(0);
        // tile boundary: next tile fully landed; keep 6 in flight (never 0
        // until the pipeline drains at the end).
        if (t + 2 < nk)      { asm volatile("s_waitcnt vmcnt(6)" ::: "memory"); }
        else if (t + 1 < nk) { asm volatile("s_waitcnt vmcnt(0)" ::: "memory"); }
        BAR();
        buf = (buf == 2) ? 0 : buf + 1;
    }
#undef STAGE_A
#undef STAGE_B
#undef BAR
#undef LGKM0

    // epilogue: C/D layout col=lane&15, row=(lane>>4)*4+reg  [measured m89]
#pragma unroll
    for (int m = 0; m < 4; ++m) {
#pragma unroll
        for (int n = 0; n < 4; ++n) {
            const size_t col = col0 + wn * 64 + n * 16 + rl;
            const size_t row = row0 + wm * 64 + m * 16 + g * 4;
            float bv = (MODE == 0) ? bias[col] : 0.f;
#pragma unroll
            for (int j = 0; j < 4; ++j) {
                float v = acc[m][n][j];
                if (MODE == 0) {
                    v += bv;
                    if ((int)col < HH) {
                        float vc = fminf(fmaxf(v, -15.f), 15.f);
                        float e = __expf(2.f * vc);
                        v = __fdividef(e - 1.f, e + 1.f);          // tanh
                    } else {
                        v = __fdividef(1.f, 1.f + __expf(-v));     // sigmoid
                    }
                }
                C[(row + j) * (size_t)N + col] = (_Float16)v;
            }
        }
    }
}

// ============ segmented forget-mult scan (3 kernels) =======================
// chain t = b*H + h (32768). Chunk of nS steps split into NSEG segments of
// SL = nS/NSEG. Affine composition: over a segment, c_out = A*c_in + B with
// A = prod(1-f), B = local scan from 0. Exact in fp32 (same arithmetic).

__global__ __launch_bounds__(256)
void scan_p1(const _Float16* __restrict__ Y, float* __restrict__ Aseg,
             float* __restrict__ Bseg, int SL)
{
    const int t = blockIdx.x * 256 + threadIdx.x;
    const int g = blockIdx.y;
    const int h = t & (HID - 1);
    const int b = t >> 10;
    const _Float16* pz = Y + ((size_t)(g * SL) * BATCH + b) * G3H + h;
    const size_t strideY = (size_t)BATCH * G3H;
    float A = 1.f, Bv = 0.f;
#pragma unroll 4
    for (int k = 0; k < SL; ++k) {
        float z = (float)pz[0];
        float f = (float)pz[HID];
        Bv = f * z + (1.f - f) * Bv;
        A *= (1.f - f);
        pz += strideY;
    }
    Aseg[(size_t)g * NCHAIN + t] = A;
    Bseg[(size_t)g * NCHAIN + t] = Bv;
}

__global__ __launch_bounds__(256)
void scan_mid(const float* __restrict__ Aseg, const float* __restrict__ Bseg,
              float* __restrict__ cst, float* __restrict__ carry,
              float* __restrict__ hid, int first)
{
    const int t = blockIdx.x * 256 + threadIdx.x;
    float c = first ? 0.f : carry[t];
#pragma unroll
    for (int g = 0; g < NSEG; ++g) {
        cst[(size_t)g * NCHAIN + t] = c;
        c = Bseg[(size_t)g * NCHAIN + t] + Aseg[(size_t)g * NCHAIN + t] * c;
    }
    carry[t] = c;
    if (hid) hid[t] = c;
}

__global__ __launch_bounds__(256)
void scan_p2(const _Float16* __restrict__ Y, const float* __restrict__ cst,
             _Float16* __restrict__ Ho, int SL)
{
    const int t = blockIdx.x * 256 + threadIdx.x;
    const int g = blockIdx.y;
    const int h = t & (HID - 1);
    const int b = t >> 10;
    const _Float16* pz = Y + ((size_t)(g * SL) * BATCH + b) * G3H + h;
    _Float16* po = Ho + ((size_t)(g * SL) * BATCH + b) * HID + h;
    const size_t strideY = (size_t)BATCH * G3H;
    const size_t strideH = (size_t)BATCH * HID;
    float c = cst[(size_t)g * NCHAIN + t];
#pragma unroll 4
    for (int k = 0; k < SL; ++k) {
        float z = (float)pz[0];
        float f = (float)pz[HID];
        float o = (float)pz[2 * HID];
        c = f * z + (1.f - f) * c;
        *po = (_Float16)(o * c);
        pz += strideY;
        po += strideH;
    }
}

// ---------------- LayerNorm over last dim (512) ----------------
template<int OUT32>
__global__ __launch_bounds__(256)
void ln_kernel(const _Float16* __restrict__ Xin, const float* __restrict__ g,
               const float* __restrict__ be, _Float16* __restrict__ o16,
               float* __restrict__ o32)
{
    const int row  = blockIdx.x * 4 + (threadIdx.x >> 6);
    const int lane = threadIdx.x & 63;
    const _Float16* p = Xin + (size_t)row * PROJ + lane * 8;
    f16x8 v = *(const f16x8*)p;
    float x[8];
    float s = 0.f;
#pragma unroll
    for (int j = 0; j < 8; ++j) { x[j] = (float)v[j]; s += x[j]; }
#pragma unroll
    for (int d = 1; d < 64; d <<= 1) s += __shfl_xor(s, d);
    const float mu = s * (1.f / PROJ);
    float s2 = 0.f;
#pragma unroll
    for (int j = 0; j < 8; ++j) { float dd = x[j] - mu; s2 += dd * dd; }
#pragma unroll
    for (int d = 1; d < 64; d <<= 1) s2 += __shfl_xor(s2, d);
    const float rstd = rsqrtf(s2 * (1.f / PROJ) + 1e-5f);

    float y[8];
#pragma unroll
    for (int j = 0; j < 8; ++j)
        y[j] = (x[j] - mu) * rstd * g[lane * 8 + j] + be[lane * 8 + j];

    if (OUT32) {
        float* q = o32 + (size_t)row * PROJ + lane * 8;
        ((float4*)q)[0] = make_float4(y[0], y[1], y[2], y[3]);
        ((float4*)q)[1] = make_float4(y[4], y[5], y[6], y[7]);
    } else {
        f16x8 o;
#pragma unroll
        for (int j = 0; j < 8; ++j) o[j] = (_Float16)y[j];
        *(f16x8*)(o16 + (size_t)row * PROJ + lane * 8) = o;
    }
}

// ---------------- launch ----------------
extern "C" void kernel_launch(void* const* d_in, const int* in_sizes, int n_in,
                              void* d_out, int out_size, void* d_ws, size_t ws_size,
                              hipStream_t stream)
{
    const float* X     = (const float*)d_in[0];
    const float* W     = (const float*)d_in[1];
    const float* b     = (const float*)d_in[2];
    const float* P     = (const float*)d_in[3];
    const float* gamma = (const float*)d_in[4];
    const float* beta  = (const float*)d_in[5];
    float* out = (float*)d_out;

    // allow 144 KiB dynamic LDS for the GEMM kernels (idempotent host call)
    (void)hipFuncSetAttribute((const void*)&gemm_lds<0>,
                              hipFuncAttributeMaxDynamicSharedMemorySize, 147456);
    (void)hipFuncSetAttribute((const void*)&gemm_lds<1>,
                              hipFuncAttributeMaxDynamicSharedMemorySize, 147456);

    // ---- ws layout: fixed buffers, then S-chunked transient buffers ----
    char* w = (char*)d_ws;
    _Float16* Xh = (_Float16*)w; w += (size_t)ROWS * DIN * 2;     // 64 MiB (layer input, aliased across layers)
    _Float16* Wh = (_Float16*)w; w += (size_t)2 * G3H * DIN * 2;  // 6 MiB
    _Float16* Ph = (_Float16*)w; w += (size_t)2 * PROJ * HID * 2; // 2 MiB
    float* carry = (float*)w;    w += (size_t)NCHAIN * 4;         // 128 KiB
    float* Aseg  = (float*)w;    w += (size_t)NSEG * NCHAIN * 4;  // 2 MiB
    float* Bseg  = (float*)w;    w += (size_t)NSEG * NCHAIN * 4;  // 2 MiB
    float* cst   = (float*)w;    w += (size_t)NSEG * NCHAIN * 4;  // 2 MiB
    const size_t fixed = (size_t)(w - (char*)d_ws);

    // largest S-chunk that fits: per-chunk = CS*32*(3H+H+PROJ)*2 bytes
    const int cands[7] = {2048, 1024, 512, 256, 128, 64, 32};
    int CS = 32;
    for (int i = 0; i < 7; ++i) {
        size_t need = fixed + (size_t)cands[i] * 32 * (G3H + HID + PROJ) * 2;
        if (need <= ws_size) { CS = cands[i]; break; }
    }
    _Float16* Yg = (_Float16*)w; w += (size_t)CS * 32 * G3H * 2;  // gates chunk
    _Float16* Ho = (_Float16*)w; w += (size_t)CS * 32 * HID * 2;  // gated output chunk
    _Float16* G2 = (_Float16*)w;                                   // proj chunk

    cvt_f32_f16<<<(ROWS * DIN / 4 + 255) / 256, 256, 0, stream>>>(X, Xh, ROWS * DIN / 4);
    cvt_f32_f16<<<(2 * G3H * DIN / 4 + 255) / 256, 256, 0, stream>>>(W, Wh, 2 * G3H * DIN / 4);
    cvt_f32_f16<<<(2 * PROJ * HID / 4 + 255) / 256, 256, 0, stream>>>(P, Ph, 2 * PROJ * HID / 4);

    float* hid = out + (size_t)ROWS * PROJ;   // next_hidden region of d_out
    const int nch = SEQ / CS;
    const int rows = CS * BATCH;              // rows per chunk (multiple of 256)
    const int SL = CS / NSEG;                 // segment length

    for (int i = 0; i < 2; ++i) {
        for (int ch = 0; ch < nch; ++ch) {
            const size_t r0 = (size_t)ch * rows;
            // gates = act(inp @ W[i]^T + b[i])
            gemm_lds<0><<<dim3(G3H / 128, rows / 256), 512, 147456, stream>>>(
                Xh + r0 * DIN, Wh + (size_t)i * G3H * DIN, b + i * G3H, Yg, G3H, DIN, HID);
            // segmented forget-mult scan
            scan_p1<<<dim3(NCHAIN / 256, NSEG), 256, 0, stream>>>(Yg, Aseg, Bseg, SL);
            scan_mid<<<NCHAIN / 256, 256, 0, stream>>>(
                Aseg, Bseg, cst, carry,
                (ch == nch - 1) ? hid + (size_t)i * NCHAIN : nullptr, ch == 0);
            scan_p2<<<dim3(NCHAIN / 256, NSEG), 256, 0, stream>>>(Yg, cst, Ho, SL);
            // projection
            gemm_lds<1><<<dim3(PROJ / 128, rows / 256), 512, 147456, stream>>>(
                Ho, Ph + (size_t)i * PROJ * HID, nullptr, G2, PROJ, HID, 0);
            // layernorm: layer 0 -> fp16 back into Xh (rows already consumed)
            if (i == 0)
                ln_kernel<0><<<rows / 4, 256, 0, stream>>>(G2, gamma, beta, Xh + r0 * PROJ, nullptr);
            else
                ln_kernel<1><<<rows / 4, 256, 0, stream>>>(G2, gamma + PROJ, beta + PROJ, nullptr, out + r0 * PROJ);
        }
    }
}